// Round 1
// baseline (152.174 us; speedup 1.0000x reference)
//
#include <hip/hip_runtime.h>

// BCH truncated series on 3D periodic velocity fields.
// out_i = L_i + R_i + 0.25 * sum_j [ (L_i(+e_j)-L_i(-e_j))*R_j - (R_i(+e_j)-R_i(-e_j))*L_j ]
// Layout is channels-first (B, D, X, Y, Z); derivatives are purely spatial so
// we compute directly in this layout (reference's moveaxis is a no-op for us).

namespace {
constexpr int Xd = 128, Yd = 128, Zd = 128, Bd = 2, Dd = 3;
constexpr int Sd  = Xd * Yd * Zd;   // channel stride
constexpr int YZd = Yd * Zd;        // x stride

__device__ inline float4 f4sub(float4 a, float4 b) {
    return make_float4(a.x - b.x, a.y - b.y, a.z - b.z, a.w - b.w);
}
__device__ inline float4 f4add(float4 a, float4 b) {
    return make_float4(a.x + b.x, a.y + b.y, a.z + b.z, a.w + b.w);
}
__device__ inline float4 f4mul(float4 a, float4 b) {
    return make_float4(a.x * b.x, a.y * b.y, a.z * b.z, a.w * b.w);
}
// d = a*b + c (per component)
__device__ inline float4 f4fma(float4 a, float4 b, float4 c) {
    return make_float4(fmaf(a.x, b.x, c.x), fmaf(a.y, b.y, c.y),
                       fmaf(a.z, b.z, c.z), fmaf(a.w, b.w, c.w));
}
// d = c - a*b (per component)
__device__ inline float4 f4fms(float4 a, float4 b, float4 c) {
    return make_float4(fmaf(-a.x, b.x, c.x), fmaf(-a.y, b.y, c.y),
                       fmaf(-a.z, b.z, c.z), fmaf(-a.w, b.w, c.w));
}
} // namespace

__global__ void __launch_bounds__(256)
bch_kernel(const float* __restrict__ L, const float* __restrict__ R,
           float* __restrict__ O)
{
    const int tid = blockIdx.x * 256 + threadIdx.x;   // 0 .. B*X*Y*(Z/4)-1
    const int z0  = (tid & 31) << 2;                  // 4-wide z chunk, 16B aligned
    int t = tid >> 5;
    const int y = t & 127; t >>= 7;
    const int x = t & 127;
    const int b = t >> 7;

    const int base = b * (Dd * Sd) + x * YZd + y * Zd + z0;

    // Relative offsets to wrapped neighbors (multiples of 128 floats for x/y,
    // so neighbor float4 loads stay 16B-aligned).
    const int oxp = (((x + 1) & 127) - x) * YZd;
    const int oxm = (((x - 1) & 127) - x) * YZd;
    const int oyp = (((y + 1) & 127) - y) * Zd;
    const int oym = (((y - 1) & 127) - y) * Zd;
    const int ozm = ((z0 - 1) & 127) - z0;   // scalar at z0-1 (wrapped)
    const int ozp = ((z0 + 4) & 127) - z0;   // scalar at z0+4 (wrapped)

    // Centers of all 3 channels for both fields (reused by every Jacobian term).
    float4 Lc[3], Rc[3];
#pragma unroll
    for (int d = 0; d < 3; ++d) {
        Lc[d] = *(const float4*)(L + base + d * Sd);
        Rc[d] = *(const float4*)(R + base + d * Sd);
    }

#pragma unroll
    for (int i = 0; i < 3; ++i) {
        const float* lp = L + base + i * Sd;
        const float* rp = R + base + i * Sd;

        // j = 0 (x direction)
        float4 dl = f4sub(*(const float4*)(lp + oxp), *(const float4*)(lp + oxm));
        float4 dr = f4sub(*(const float4*)(rp + oxp), *(const float4*)(rp + oxm));
        float4 br = f4fms(dr, Lc[0], f4mul(dl, Rc[0]));

        // j = 1 (y direction)
        dl = f4sub(*(const float4*)(lp + oyp), *(const float4*)(lp + oym));
        dr = f4sub(*(const float4*)(rp + oyp), *(const float4*)(rp + oym));
        br = f4fms(dr, Lc[1], f4fma(dl, Rc[1], br));

        // j = 2 (z direction): shift-in-register from center + 2 wrapped scalars
        const float lzm = lp[ozm], lzp = lp[ozp];
        const float rzm = rp[ozm], rzp = rp[ozp];
        dl = make_float4(Lc[i].y - lzm, Lc[i].z - Lc[i].x,
                         Lc[i].w - Lc[i].y, lzp - Lc[i].z);
        dr = make_float4(Rc[i].y - rzm, Rc[i].z - Rc[i].x,
                         Rc[i].w - Rc[i].y, rzp - Rc[i].z);
        br = f4fms(dr, Lc[2], f4fma(dl, Rc[2], br));

        // out_i = L_i + R_i + 0.25 * br   (0.5 from Jacobian * 0.5 from BCH)
        float4 out = f4add(Lc[i], Rc[i]);
        const float4 q = make_float4(0.25f, 0.25f, 0.25f, 0.25f);
        out = f4fma(q, br, out);

        *(float4*)(O + base + i * Sd) = out;
    }
}

extern "C" void kernel_launch(void* const* d_in, const int* in_sizes, int n_in,
                              void* d_out, int out_size, void* d_ws, size_t ws_size,
                              hipStream_t stream)
{
    const float* L = (const float*)d_in[0];
    const float* R = (const float*)d_in[1];
    float*       O = (float*)d_out;

    const int nthreads = Bd * Xd * Yd * (Zd / 4);   // 1,048,576
    dim3 grid(nthreads / 256), block(256);          // 4096 blocks
    bch_kernel<<<grid, block, 0, stream>>>(L, R, O);
}